// Round 12
// baseline (433.085 us; speedup 1.0000x reference)
//
#include <hip/hip_runtime.h>

typedef unsigned short u16;
typedef short short8_t __attribute__((ext_vector_type(8)));
typedef float floatx4 __attribute__((ext_vector_type(4)));

static constexpr int N_USER_C = 100000;
static constexpr int N_PC_C   = 20000;
static constexpr int N_URL_C  = 50000;
static constexpr int E_UP_C   = 250000;
static constexpr int E_UU_C   = 500000;

// padded-CSR strides (Poisson degree tails: overflow prob negligible at these bounds)
static constexpr int S_UPD = 48;   // up_dst mean 12.5
static constexpr int S_UUD = 40;   // uu_dst mean 10
static constexpr int S_SRC = 24;   // up_src mean 2.5 / uu_src mean 5

__device__ __forceinline__ float bf2f(u16 h) {
    return __uint_as_float(((unsigned)h) << 16);
}
__device__ __forceinline__ u16 f2bf(float f) {
    unsigned u = __float_as_uint(f);
    u += 0x7fffu + ((u >> 16) & 1u);
    return (u16)(u >> 16);
}

// ---------------- merged prep+fill: fill (1960) | wcvt (768) | proj3 (10625) ----------------
// Fill blocks FIRST: latency-bound atomic CSR fill starts immediately; prep blocks
// (VALU/BW-bound) co-schedule into its latency bubbles. Write-BW-bound end to end (R9 PMC).
struct PFArgs {
    const float* wsrc[12];
    u16* wdst;
    const float *Xu, *Wu, *bu, *Xp, *Wp, *bp, *Xr, *Wr, *br;
    u16 *ou, *op, *orr;
    const int *up_src, *up_dst, *uu_src, *uu_dst;
    int *cnt_up_dst, *cnt_uu_dst, *cnt_up_src, *cnt_uu_src;
    int *val_up_dst, *val_uu_dst;
    u16 *val_up_src, *val_uu_src;
};
__global__ __launch_bounds__(256) void prepfill_kernel(PFArgs a)
{
    int b = blockIdx.x, tid = threadIdx.x;
    if (b < 1960) {
        const int range = b & 7;
        const int ebase = (b >> 3) * 2048 + tid;
#pragma unroll
        for (int i = 0; i < 8; ++i) {
            int e = ebase + i * 256;
            if (e < E_UP_C) {
                int s = __builtin_nontemporal_load(a.up_src + e);
                int d = __builtin_nontemporal_load(a.up_dst + e);
                if (d / 2500 == range) {
                    int p = atomicAdd(&a.cnt_up_dst[d], 1);
                    if (p < S_UPD) a.val_up_dst[d * S_UPD + p] = s;
                }
                if (s / 12500 == range) {
                    int p = atomicAdd(&a.cnt_up_src[s], 1);
                    if (p < S_SRC) a.val_up_src[s * S_SRC + p] = (u16)d;
                }
            }
            if (e < E_UU_C) {
                int s = __builtin_nontemporal_load(a.uu_src + e);
                int d = __builtin_nontemporal_load(a.uu_dst + e);
                if (d / 6250 == range) {
                    int p = atomicAdd(&a.cnt_uu_dst[d], 1);
                    if (p < S_UUD) a.val_uu_dst[d * S_UUD + p] = s;
                }
                if (s / 12500 == range) {
                    int p = atomicAdd(&a.cnt_uu_src[s], 1);
                    if (p < S_SRC) a.val_uu_src[s * S_SRC + p] = (u16)d;
                }
            }
        }
    } else if (b < 1960 + 768) {
        int idx = (b - 1960) * 256 + tid;
        int m = idx >> 14, e = idx & 16383;
        int n = e >> 7, k = e & 127;
        int Nm = (m == 11) ? 64 : 128;
        u16 v = 0;
        if (n < Nm) v = f2bf(a.wsrc[m][k * Nm + n]);
        a.wdst[(size_t)m * 16384 + n * 128 + k] = v;
    } else {
        int idx = (b - 1960 - 768) * 256 + tid;
        const float* X; const float* W; const float* bi; u16* o; int K;
        if (idx < 1600000)       { X = a.Xu; W = a.Wu; bi = a.bu; o = a.ou; K = 6; }
        else if (idx < 1920000)  { idx -= 1600000; X = a.Xp; W = a.Wp; bi = a.bp; o = a.op; K = 4; }
        else                     { idx -= 1920000; X = a.Xr; W = a.Wr; bi = a.br; o = a.orr; K = 3; }
        int r = idx >> 4, c0 = (idx & 15) * 8;
        float acc[8];
        {
            const float4 b0 = *(const float4*)(bi + c0);
            const float4 b1 = *(const float4*)(bi + c0 + 4);
            acc[0] = b0.x; acc[1] = b0.y; acc[2] = b0.z; acc[3] = b0.w;
            acc[4] = b1.x; acc[5] = b1.y; acc[6] = b1.z; acc[7] = b1.w;
        }
        for (int k = 0; k < K; ++k) {
            float xk = X[(size_t)r * K + k];
            const float4 w0 = *(const float4*)(W + k * 128 + c0);
            const float4 w1 = *(const float4*)(W + k * 128 + c0 + 4);
            acc[0] += xk * w0.x; acc[1] += xk * w0.y; acc[2] += xk * w0.z; acc[3] += xk * w0.w;
            acc[4] += xk * w1.x; acc[5] += xk * w1.y; acc[6] += xk * w1.z; acc[7] += xk * w1.w;
        }
        uint4 pk;
        pk.x = (unsigned)f2bf(acc[0]) | ((unsigned)f2bf(acc[1]) << 16);
        pk.y = (unsigned)f2bf(acc[2]) | ((unsigned)f2bf(acc[3]) << 16);
        pk.z = (unsigned)f2bf(acc[4]) | ((unsigned)f2bf(acc[5]) << 16);
        pk.w = (unsigned)f2bf(acc[6]) | ((unsigned)f2bf(acc[7]) << 16);
        *(uint4*)(o + (size_t)r * 128 + c0) = pk;
    }
}

// ---------------- gather mean row helper: unroll x4, 4 independent chains ----------------
__device__ __forceinline__ void gm_row(
    const u16* __restrict__ feat, const int* __restrict__ cnt,
    const int* __restrict__ vals, int stride, u16* __restrict__ outp, int row, int lane)
{
    int deg = cnt[row];
    deg = __builtin_amdgcn_readfirstlane(deg);
    int n = deg < stride ? deg : stride;
    const int* vp = vals + row * stride;
    float a0 = 0.f, a1 = 0.f, b0 = 0.f, b1 = 0.f;
    float c0 = 0.f, c1 = 0.f, d0 = 0.f, d1 = 0.f;
    int j = 0;
    for (; j + 4 <= n; j += 4) {
        int i0 = __builtin_nontemporal_load(vp + j);
        int i1 = __builtin_nontemporal_load(vp + j + 1);
        int i2 = __builtin_nontemporal_load(vp + j + 2);
        int i3 = __builtin_nontemporal_load(vp + j + 3);
        unsigned u0 = *(const unsigned*)(feat + (size_t)i0 * 128 + lane * 2);
        unsigned u1 = *(const unsigned*)(feat + (size_t)i1 * 128 + lane * 2);
        unsigned u2 = *(const unsigned*)(feat + (size_t)i2 * 128 + lane * 2);
        unsigned u3 = *(const unsigned*)(feat + (size_t)i3 * 128 + lane * 2);
        a0 += bf2f((u16)(u0 & 0xffff)); a1 += bf2f((u16)(u0 >> 16));
        b0 += bf2f((u16)(u1 & 0xffff)); b1 += bf2f((u16)(u1 >> 16));
        c0 += bf2f((u16)(u2 & 0xffff)); c1 += bf2f((u16)(u2 >> 16));
        d0 += bf2f((u16)(u3 & 0xffff)); d1 += bf2f((u16)(u3 >> 16));
    }
    for (; j < n; ++j) {
        int i0 = __builtin_nontemporal_load(vp + j);
        unsigned u0 = *(const unsigned*)(feat + (size_t)i0 * 128 + lane * 2);
        a0 += bf2f((u16)(u0 & 0xffff)); a1 += bf2f((u16)(u0 >> 16));
    }
    float ax = (a0 + b0) + (c0 + d0), ay = (a1 + b1) + (c1 + d1);
    float inv = 1.0f / fmaxf((float)deg, 1.0f);
    unsigned o = (unsigned)f2bf(ax * inv) | ((unsigned)f2bf(ay * inv) << 16);
    *(unsigned*)(outp + (size_t)row * 128 + lane * 2) = o;
}

// ---------------- merged mean-gathers + user@Wctx GEMM (independent work, one dispatch) ----
// blocks [0,782): enr = user@Wctx + bctx (MFMA, 128 rows/block) — FIRST so the scarce
// MFMA blocks launch immediately and overlap the latency-bound gathers.
// blocks [782, 782+5000): pc mean rows; [5782, 18282): url mean rows.
__global__ __launch_bounds__(256) void mean_ctx_kernel(
    const u16* __restrict__ feat,
    const int* __restrict__ cnt_pc, const int* __restrict__ val_pc, u16* __restrict__ out_pc,
    const int* __restrict__ cnt_url, const int* __restrict__ val_url, u16* __restrict__ out_url,
    const u16* __restrict__ Wctx_t, const float* __restrict__ bctx, u16* __restrict__ enr)
{
    __shared__ u16 Ws[2][128 * 40];         // 20 KB (GEMM path only) -> 8 blocks/CU
    const int b = blockIdx.x, tid = threadIdx.x;
    const int wave = tid >> 6, lane = tid & 63;

    if (b >= 782) {
        int bg = b - 782;
        if (bg < 5000) gm_row(feat, cnt_pc, val_pc, S_UPD, out_pc, bg * 4 + wave, lane);
        else           gm_row(feat, cnt_url, val_url, S_UUD, out_url, (bg - 5000) * 4 + wave, lane);
        return;
    }

    // ---- user@Wctx GEMM: 128 rows/block, wave owns 32 (2 mtiles) ----
    const int m = lane & 15, kq = lane >> 4;
    const int rbase = b * 128 + wave * 32;
    const int sn = tid >> 1, spart = tid & 1;
    const int M = N_USER_C;

    floatx4 acc[2][8];
#pragma unroll
    for (int mt = 0; mt < 2; ++mt)
#pragma unroll
        for (int nt = 0; nt < 8; ++nt) acc[mt][nt] = (floatx4)0.0f;

    auto stageW = [&](int kc, int buf) {
        *(short8_t*)&Ws[buf][sn * 40 + spart * 16] =
            *(const short8_t*)(Wctx_t + (size_t)sn * 128 + kc + spart * 16);
        *(short8_t*)&Ws[buf][sn * 40 + spart * 16 + 8] =
            *(const short8_t*)(Wctx_t + (size_t)sn * 128 + kc + spart * 16 + 8);
    };
    auto loadA = [&](int kc, int mt) -> short8_t {
        int row = rbase + mt * 16 + m; row = row < M ? row : M - 1;
        return *(const short8_t*)(feat + (size_t)row * 128 + kc + kq * 8);
    };

    stageW(0, 0);
    short8_t an0 = loadA(0, 0), an1 = loadA(0, 1);
    __syncthreads();
    for (int c = 0; c < 4; ++c) {
        int c1 = c + 1;
        if (c1 < 4) stageW(c1 * 32, c1 & 1);
        short8_t a0 = an0, a1 = an1;
        if (c1 < 4) { an0 = loadA(c1 * 32, 0); an1 = loadA(c1 * 32, 1); }
#pragma unroll
        for (int nt = 0; nt < 8; ++nt) {
            short8_t bb = *(const short8_t*)&Ws[c & 1][(nt * 16 + m) * 40 + kq * 8];
            acc[0][nt] = __builtin_amdgcn_mfma_f32_16x16x32_bf16(a0, bb, acc[0][nt], 0, 0, 0);
            acc[1][nt] = __builtin_amdgcn_mfma_f32_16x16x32_bf16(a1, bb, acc[1][nt], 0, 0, 0);
        }
        __syncthreads();
    }
    // C/D layout: col = lane&15, row = (lane>>4)*4 + r
#pragma unroll
    for (int nt = 0; nt < 8; ++nt) {
        int col = nt * 16 + m;
        float bv = bctx[col];
#pragma unroll
        for (int mt = 0; mt < 2; ++mt)
#pragma unroll
            for (int r = 0; r < 4; ++r) {
                int row = rbase + mt * 16 + kq * 4 + r;
                if (row < M) enr[(size_t)row * 128 + col] = f2bf(acc[mt][nt][r] + bv);
            }
    }
}

// ---------------- fused 3-stage MFMA GEMM (pc/url chains), double-buffered W ----------------
// x1 = relu(mean@Wl0 + x0@Wr0 + b0)       [x1 -> LDS]
// x2 = relu(mean@Wl1 + x1@Wr1 + b1 + x1)  [x2 -> LDS]
// out = x2@Wc                             [-> global]
struct FSeg {
    const u16 *mean, *x0;
    const u16 *Wl0, *Wr0, *Wl1, *Wr1, *Wc;
    const float *b0, *b1;
    u16* out; int M; int bstart;
};
struct FArgs { FSeg s[2]; };

__global__ __launch_bounds__(256) void chain_kernel(FArgs fa)
{
    constexpr int XP = 136;                 // x_tile stride in u16
    __shared__ u16 Ws[2][128 * 40];         // 2 x 10 KB weight chunks (double buffer)
    __shared__ u16 Xs[128 * XP];            // 34 KB activation tile

    int si = ((int)blockIdx.x >= fa.s[1].bstart) ? 1 : 0;
    FSeg sg = fa.s[si];
    const int bb = blockIdx.x - sg.bstart;

    const int tid = threadIdx.x;
    const int wave = tid >> 6, lane = tid & 63;
    const int m = lane & 15, kq = lane >> 4;
    const int rloc = wave * 32;
    const int rbase = bb * 128 + rloc;
    const int sn = tid >> 1, spart = tid & 1;

    floatx4 acc[2][8];

    auto zeroAcc = [&]() {
#pragma unroll
        for (int mt = 0; mt < 2; ++mt)
#pragma unroll
            for (int nt = 0; nt < 8; ++nt) acc[mt][nt] = (floatx4)0.0f;
    };
    auto stageW = [&](const u16* Wt, int kc, int buf) {
        *(short8_t*)&Ws[buf][sn * 40 + spart * 16] =
            *(const short8_t*)(Wt + (size_t)sn * 128 + kc + spart * 16);
        *(short8_t*)&Ws[buf][sn * 40 + spart * 16 + 8] =
            *(const short8_t*)(Wt + (size_t)sn * 128 + kc + spart * 16 + 8);
    };
    auto loadAg = [&](const u16* A, int kc, int mt) -> short8_t {
        int row = rbase + mt * 16 + m; row = row < sg.M ? row : sg.M - 1;
        return *(const short8_t*)(A + (size_t)row * 128 + kc + kq * 8);
    };
    auto loadAs = [&](int kc, int mt) -> short8_t {
        return *(const short8_t*)&Xs[(rloc + mt * 16 + m) * XP + kc + kq * 8];
    };
    auto mfmaChunk = [&](short8_t a0, short8_t a1, int buf) {
#pragma unroll
        for (int nt = 0; nt < 8; ++nt) {
            short8_t b = *(const short8_t*)&Ws[buf][(nt * 16 + m) * 40 + kq * 8];
            acc[0][nt] = __builtin_amdgcn_mfma_f32_16x16x32_bf16(a0, b, acc[0][nt], 0, 0, 0);
            acc[1][nt] = __builtin_amdgcn_mfma_f32_16x16x32_bf16(a1, b, acc[1][nt], 0, 0, 0);
        }
    };
    auto passDual = [&](const u16* W1, const u16* A1g, const u16* W2, const u16* A2g, bool a2lds) {
        zeroAcc();
        stageW(W1, 0, 0);
        short8_t an0 = loadAg(A1g, 0, 0), an1 = loadAg(A1g, 0, 1);
        __syncthreads();
        for (int c = 0; c < 8; ++c) {
            int c1 = c + 1;
            if (c1 < 8) {
                int kc1 = (c1 & 3) * 32;
                stageW(c1 < 4 ? W1 : W2, kc1, c1 & 1);
            }
            short8_t a0 = an0, a1 = an1;
            if (c1 < 8) {
                int kc1 = (c1 & 3) * 32;
                if (c1 < 4)     { an0 = loadAg(A1g, kc1, 0); an1 = loadAg(A1g, kc1, 1); }
                else if (a2lds) { an0 = loadAs(kc1, 0);      an1 = loadAs(kc1, 1); }
                else            { an0 = loadAg(A2g, kc1, 0); an1 = loadAg(A2g, kc1, 1); }
            }
            mfmaChunk(a0, a1, c & 1);
            __syncthreads();
        }
    };
    auto passSingleLds = [&](const u16* W1) {
        zeroAcc();
        stageW(W1, 0, 0);
        short8_t an0 = loadAs(0, 0), an1 = loadAs(0, 1);
        __syncthreads();
        for (int c = 0; c < 4; ++c) {
            int c1 = c + 1;
            if (c1 < 4) stageW(W1, c1 * 32, c1 & 1);
            short8_t a0 = an0, a1 = an1;
            if (c1 < 4) { an0 = loadAs(c1 * 32, 0); an1 = loadAs(c1 * 32, 1); }
            mfmaChunk(a0, a1, c & 1);
            __syncthreads();
        }
    };
    // C/D layout: col = lane&15, row = (lane>>4)*4 + r; wave epilogues touch only their
    // own 32-row band (same band as their A-frag LDS reads) -> no cross-wave hazard.
    auto epilogueToLds = [&](const float* bias, bool addRes) {
#pragma unroll
        for (int nt = 0; nt < 8; ++nt) {
            int col = nt * 16 + m;
            float bv = bias[col];
#pragma unroll
            for (int mt = 0; mt < 2; ++mt)
#pragma unroll
                for (int r = 0; r < 4; ++r) {
                    int lrow = rloc + mt * 16 + kq * 4 + r;
                    float v = acc[mt][nt][r] + bv;
                    if (addRes) v += bf2f(Xs[lrow * XP + col]);
                    Xs[lrow * XP + col] = f2bf(fmaxf(v, 0.f));
                }
        }
        __syncthreads();   // order LDS epilogue writes before next pass's cross-lane reads
    };
    auto epilogueToGlobal = [&](u16* outp) {
#pragma unroll
        for (int nt = 0; nt < 8; ++nt) {
            int col = nt * 16 + m;
#pragma unroll
            for (int mt = 0; mt < 2; ++mt)
#pragma unroll
                for (int r = 0; r < 4; ++r) {
                    int row = rbase + mt * 16 + kq * 4 + r;
                    if (row < sg.M) outp[(size_t)row * 128 + col] = f2bf(acc[mt][nt][r]);
                }
        }
    };

    passDual(sg.Wl0, sg.mean, sg.Wr0, sg.x0, false);
    epilogueToLds(sg.b0, false);
    passDual(sg.Wl1, sg.mean, sg.Wr1, nullptr, true);
    epilogueToLds(sg.b1, true);
    passSingleLds(sg.Wc);
    epilogueToGlobal(sg.out);
}

// ---------------- fused ctx-gather + classifier: enr read once, h never in global ----------
// Block = 64 user rows; wave owns 16. Phase A: gather-accumulate enr rows in fp32
// registers, write bf16 to LDS Xs. __syncthreads. Phase B: MFMA classifier + reduce.
__global__ __launch_bounds__(256) void ctx_final_kernel(
    const u16* __restrict__ enr,
    const int* __restrict__ cnt_up, const u16* __restrict__ val_up, const u16* __restrict__ pcW,
    const int* __restrict__ cnt_uu, const u16* __restrict__ val_uu, const u16* __restrict__ urlW,
    const u16* __restrict__ Wc1_t, const float* __restrict__ bc1,
    const float* __restrict__ Wc2, const float* __restrict__ bc2,
    float* __restrict__ out, int M)
{
    __shared__ u16 Xs[64 * 136];               // 17.4 KB enr' tile (bf16)
    __shared__ u16 Wc1s[64 * 136];             // 17.4 KB Wc1 [n][k]

    const int tid = threadIdx.x;
    const int wave = tid >> 6, lane = tid & 63;
    const int m = lane & 15, kq = lane >> 4;
    const int rbw = blockIdx.x * 64 + wave * 16;

    // stage Wc1 (ordered before phase-B reads by the phase A/B barrier)
    for (int idx = tid; idx < 64 * 16; idx += 256) {
        int row = idx >> 4, part = idx & 15;
        *(short8_t*)&Wc1s[row * 136 + part * 8] =
            *(const short8_t*)(Wc1_t + (size_t)row * 128 + part * 8);
    }

    // ---- phase A: enr' rows -> Xs (each wave writes only its own 16-row band) ----
    for (int rr = 0; rr < 16; ++rr) {
        int row = rbw + rr;
        int lrow = wave * 16 + rr;
        unsigned o = 0;
        if (row < M) {
            int n0 = cnt_up[row], n1 = cnt_uu[row];
            n0 = __builtin_amdgcn_readfirstlane(n0); n1 = __builtin_amdgcn_readfirstlane(n1);
            n0 = n0 < S_SRC ? n0 : S_SRC; n1 = n1 < S_SRC ? n1 : S_SRC;
            int total = n0 + n1;
            const u16* vu = val_up + row * S_SRC;
            const u16* vr = val_uu + row * S_SRC;
            unsigned eu = *(const unsigned*)(enr + (size_t)row * 128 + lane * 2);
            float a0 = bf2f((u16)(eu & 0xffff)), a1 = bf2f((u16)(eu >> 16));
            float b0 = 0.f, b1 = 0.f, c0 = 0.f, c1 = 0.f, d0 = 0.f, d1 = 0.f;
            auto ld = [&](int t) -> unsigned {
                bool isup = t < n0;
                int idx = isup ? vu[t] : vr[t - n0];
                const u16* base = isup ? pcW : urlW;
                return *(const unsigned*)(base + (size_t)idx * 128 + lane * 2);
            };
            int t = 0;
            for (; t + 4 <= total; t += 4) {
                unsigned u0 = ld(t + 0), u1 = ld(t + 1), u2 = ld(t + 2), u3 = ld(t + 3);
                a0 += bf2f((u16)(u0 & 0xffff)); a1 += bf2f((u16)(u0 >> 16));
                b0 += bf2f((u16)(u1 & 0xffff)); b1 += bf2f((u16)(u1 >> 16));
                c0 += bf2f((u16)(u2 & 0xffff)); c1 += bf2f((u16)(u2 >> 16));
                d0 += bf2f((u16)(u3 & 0xffff)); d1 += bf2f((u16)(u3 >> 16));
            }
            for (; t < total; ++t) {
                unsigned u0 = ld(t);
                a0 += bf2f((u16)(u0 & 0xffff)); a1 += bf2f((u16)(u0 >> 16));
            }
            float ax = (a0 + b0) + (c0 + d0), ay = (a1 + b1) + (c1 + d1);
            o = (unsigned)f2bf(ax) | ((unsigned)f2bf(ay) << 16);
        }
        *(unsigned*)&Xs[lrow * 136 + 2 * lane] = o;
    }

    __syncthreads();   // LDS producer->consumer boundary (cross-lane)

    // ---- phase B: h = relu(Xs@Wc1 + bc1); out = h@Wc2 + bc2 ----
    floatx4 acc2[4];
#pragma unroll
    for (int nt = 0; nt < 4; ++nt) acc2[nt] = (floatx4)0.0f;
    for (int c = 0; c < 4; ++c) {
        int kc = c * 32;
        short8_t a = *(const short8_t*)&Xs[(wave * 16 + m) * 136 + kc + kq * 8];
#pragma unroll
        for (int nt = 0; nt < 4; ++nt) {
            short8_t b = *(const short8_t*)&Wc1s[(nt * 16 + m) * 136 + kc + kq * 8];
            acc2[nt] = __builtin_amdgcn_mfma_f32_16x16x32_bf16(a, b, acc2[nt], 0, 0, 0);
        }
    }

    float w0v[4], w1v[4], bv[4];
#pragma unroll
    for (int nt = 0; nt < 4; ++nt) {
        int col = nt * 16 + m;
        w0v[nt] = Wc2[col * 2 + 0];
        w1v[nt] = Wc2[col * 2 + 1];
        bv[nt]  = bc1[col];
    }
    float b20 = bc2[0], b21 = bc2[1];
#pragma unroll
    for (int r = 0; r < 4; ++r) {
        float o0 = 0.f, o1 = 0.f;
#pragma unroll
        for (int nt = 0; nt < 4; ++nt) {
            float v = acc2[nt][r] + bv[nt];
            v = fmaxf(v, 0.f);
            o0 += v * w0v[nt];
            o1 += v * w1v[nt];
        }
#pragma unroll
        for (int off = 1; off < 16; off <<= 1) {
            o0 += __shfl_xor(o0, off, 64);
            o1 += __shfl_xor(o1, off, 64);
        }
        if (m == 0) {
            int row = rbw + kq * 4 + r;
            if (row < M) {
                out[(size_t)row * 2 + 0] = o0 + b20;
                out[(size_t)row * 2 + 1] = o1 + b21;
            }
        }
    }
}

extern "C" void kernel_launch(void* const* d_in, const int* in_sizes, int n_in,
                              void* d_out, int out_size, void* d_ws, size_t ws_size,
                              hipStream_t stream)
{
    const float* x_user  = (const float*)d_in[0];
    const float* x_pc    = (const float*)d_in[1];
    const float* x_url   = (const float*)d_in[2];
    const int* e_up_src  = (const int*)d_in[3];
    const int* e_up_dst  = (const int*)d_in[4];
    const int* e_uu_src  = (const int*)d_in[5];
    const int* e_uu_dst  = (const int*)d_in[6];
    const float* Wu      = (const float*)d_in[7];
    const float* bu      = (const float*)d_in[8];
    const float* Wp      = (const float*)d_in[9];
    const float* bp      = (const float*)d_in[10];
    const float* Wr_feat = (const float*)d_in[11];
    const float* br_feat = (const float*)d_in[12];
    const float* Wl_pc   = (const float*)d_in[13];
    const float* bl_pc   = (const float*)d_in[14];
    const float* Wr_pc   = (const float*)d_in[15];
    const float* Wl_url  = (const float*)d_in[16];
    const float* bl_url  = (const float*)d_in[17];
    const float* Wr_url  = (const float*)d_in[18];
    const float* Wctx    = (const float*)d_in[19];
    const float* bctx    = (const float*)d_in[20];
    const float* Wc1     = (const float*)d_in[21];
    const float* bc1     = (const float*)d_in[22];
    const float* Wc2     = (const float*)d_in[23];
    const float* bc2     = (const float*)d_in[24];
    float* out = (float*)d_out;

    // ---- workspace layout (4-byte words) ----
    char* wsb = (char*)d_ws;
    u16* user_bf  = (u16*)(wsb);                            //  6,400,000 w
    u16* enr      = (u16*)(wsb + 4ull *  6400000);          //  6,400,000 w
    u16* mean_pc  = (u16*)(wsb + 4ull * 12800000);          //  1,280,000 w
    u16* mean_url = (u16*)(wsb + 4ull * 14080000);          //  3,200,000 w
    u16* pc_a     = (u16*)(wsb + 4ull * 17280000);          //  1,280,000 w
    u16* pc_b     = (u16*)(wsb + 4ull * 18560000);          //  1,280,000 w
    u16* url_a    = (u16*)(wsb + 4ull * 19840000);          //  3,200,000 w
    u16* url_b    = (u16*)(wsb + 4ull * 23040000);          //  3,200,000 w
    u16* Wt       = (u16*)(wsb + 4ull * 26240000);          //    100,000 w slot
    int* cnts     = (int*)(wsb + 4ull * 26340000);          //    270,000 w (4 count arrays)
    int* up_dst_val = (int*)(wsb + 4ull * 26610000);        //    960,000 w (20000*48)
    int* uu_dst_val = (int*)(wsb + 4ull * 27570000);        //  2,000,000 w (50000*40)
    u16* up_src_val = (u16*)(wsb + 4ull * 29570000);        //  1,200,000 w (100000*24 u16)
    u16* uu_src_val = (u16*)(wsb + 4ull * 30770000);        //  1,200,000 w

    int* cnt_up_dst = cnts + 0;
    int* cnt_uu_dst = cnts + 20000;
    int* cnt_up_src = cnts + 70000;
    int* cnt_uu_src = cnts + 170000;

    const int T = 256;

    // 0. zero CSR counters
    hipMemsetAsync(cnts, 0, 270000ull * 4, stream);

    // 1. merged prep+fill: fill (1960, first) | wcvt (768) | proj3 (10625)
    PFArgs pf;
    pf.wsrc[0] = Wl_pc;               pf.wsrc[1] = Wr_pc;
    pf.wsrc[2] = Wl_pc + 128 * 128;   pf.wsrc[3] = Wr_pc + 128 * 128;
    pf.wsrc[4] = Wl_url;              pf.wsrc[5] = Wr_url;
    pf.wsrc[6] = Wl_url + 128 * 128;  pf.wsrc[7] = Wr_url + 128 * 128;
    pf.wsrc[8] = Wctx;                pf.wsrc[9] = Wctx + 128 * 128;
    pf.wsrc[10] = Wctx + 256 * 128;   pf.wsrc[11] = Wc1;
    pf.wdst = Wt;
    pf.Xu = x_user; pf.Wu = Wu;      pf.bu = bu;      pf.ou = user_bf;
    pf.Xp = x_pc;   pf.Wp = Wp;      pf.bp = bp;      pf.op = pc_a;
    pf.Xr = x_url;  pf.Wr = Wr_feat; pf.br = br_feat; pf.orr = url_a;
    pf.up_src = e_up_src; pf.up_dst = e_up_dst;
    pf.uu_src = e_uu_src; pf.uu_dst = e_uu_dst;
    pf.cnt_up_dst = cnt_up_dst; pf.cnt_uu_dst = cnt_uu_dst;
    pf.cnt_up_src = cnt_up_src; pf.cnt_uu_src = cnt_uu_src;
    pf.val_up_dst = up_dst_val; pf.val_uu_dst = uu_dst_val;
    pf.val_up_src = up_src_val; pf.val_uu_src = uu_src_val;
    prepfill_kernel<<<1960 + 768 + 10625, T, 0, stream>>>(pf);

    // 2. merged: user@Wctx GEMM (782, first) | pc/url mean gathers (17500)
    mean_ctx_kernel<<<782 + 17500, T, 0, stream>>>(
        user_bf, cnt_up_dst, up_dst_val, mean_pc, cnt_uu_dst, uu_dst_val, mean_url,
        Wt + 8 * 16384, bctx, enr);

    // 3. pc/url 3-stage chains (depend on means)
    FArgs fg;
    fg.s[0] = { mean_pc,  pc_a,  Wt + 0 * 16384, Wt + 1 * 16384, Wt + 2 * 16384, Wt + 3 * 16384,
                Wt + 9 * 16384,  bl_pc,  bl_pc + 128,  pc_b,  N_PC_C,   0 };
    fg.s[1] = { mean_url, url_a, Wt + 4 * 16384, Wt + 5 * 16384, Wt + 6 * 16384, Wt + 7 * 16384,
                Wt + 10 * 16384, bl_url, bl_url + 128, url_b, N_URL_C,  157 };
    chain_kernel<<<548, T, 0, stream>>>(fg);

    // 4. fused ctx-gather + classifier
    ctx_final_kernel<<<(N_USER_C + 63) / 64, T, 0, stream>>>(
        enr, cnt_up_src, up_src_val, pc_b, cnt_uu_src, uu_src_val, url_b,
        Wt + 11 * 16384, bc1, Wc2, bc2, out, N_USER_C);
}

// Round 13
// 373.843 us; speedup vs baseline: 1.1585x; 1.1585x over previous
//
#include <hip/hip_runtime.h>

typedef unsigned short u16;
typedef short short8_t __attribute__((ext_vector_type(8)));
typedef float floatx4 __attribute__((ext_vector_type(4)));

static constexpr int N_USER_C = 100000;
static constexpr int N_PC_C   = 20000;
static constexpr int N_URL_C  = 50000;
static constexpr int E_UP_C   = 250000;
static constexpr int E_UU_C   = 500000;

// padded-CSR strides (Poisson degree tails: overflow prob negligible at these bounds)
static constexpr int S_UPD = 48;   // up_dst mean 12.5
static constexpr int S_UUD = 40;   // uu_dst mean 10
static constexpr int S_SRC = 24;   // up_src mean 2.5 / uu_src mean 5

__device__ __forceinline__ float bf2f(u16 h) {
    return __uint_as_float(((unsigned)h) << 16);
}
__device__ __forceinline__ u16 f2bf(float f) {
    unsigned u = __float_as_uint(f);
    u += 0x7fffu + ((u >> 16) & 1u);
    return (u16)(u >> 16);
}

// ---------------- merged prep+fill: fill (1960) | wcvt (768) | proj3 (10625) ----------------
// Both paths lean (8-16 VGPR, 0 LDS) -> safe heterogeneous merge (R12 lesson: never merge
// latency-bound work into a fat-footprint kernel).
struct PFArgs {
    const float* wsrc[12];
    u16* wdst;
    const float *Xu, *Wu, *bu, *Xp, *Wp, *bp, *Xr, *Wr, *br;
    u16 *ou, *op, *orr;
    const int *up_src, *up_dst, *uu_src, *uu_dst;
    int *cnt_up_dst, *cnt_uu_dst, *cnt_up_src, *cnt_uu_src;
    int *val_up_dst, *val_uu_dst;
    u16 *val_up_src, *val_uu_src;
};
__global__ __launch_bounds__(256) void prepfill_kernel(PFArgs a)
{
    int b = blockIdx.x, tid = threadIdx.x;
    if (b < 1960) {
        const int range = b & 7;
        const int ebase = (b >> 3) * 2048 + tid;
#pragma unroll
        for (int i = 0; i < 8; ++i) {
            int e = ebase + i * 256;
            if (e < E_UP_C) {
                int s = __builtin_nontemporal_load(a.up_src + e);
                int d = __builtin_nontemporal_load(a.up_dst + e);
                if (d / 2500 == range) {
                    int p = atomicAdd(&a.cnt_up_dst[d], 1);
                    if (p < S_UPD) a.val_up_dst[d * S_UPD + p] = s;
                }
                if (s / 12500 == range) {
                    int p = atomicAdd(&a.cnt_up_src[s], 1);
                    if (p < S_SRC) a.val_up_src[s * S_SRC + p] = (u16)d;
                }
            }
            if (e < E_UU_C) {
                int s = __builtin_nontemporal_load(a.uu_src + e);
                int d = __builtin_nontemporal_load(a.uu_dst + e);
                if (d / 6250 == range) {
                    int p = atomicAdd(&a.cnt_uu_dst[d], 1);
                    if (p < S_UUD) a.val_uu_dst[d * S_UUD + p] = s;
                }
                if (s / 12500 == range) {
                    int p = atomicAdd(&a.cnt_uu_src[s], 1);
                    if (p < S_SRC) a.val_uu_src[s * S_SRC + p] = (u16)d;
                }
            }
        }
    } else if (b < 1960 + 768) {
        int idx = (b - 1960) * 256 + tid;
        int m = idx >> 14, e = idx & 16383;
        int n = e >> 7, k = e & 127;
        int Nm = (m == 11) ? 64 : 128;
        u16 v = 0;
        if (n < Nm) v = f2bf(a.wsrc[m][k * Nm + n]);
        a.wdst[(size_t)m * 16384 + n * 128 + k] = v;
    } else {
        int idx = (b - 1960 - 768) * 256 + tid;
        const float* X; const float* W; const float* bi; u16* o; int K;
        if (idx < 1600000)       { X = a.Xu; W = a.Wu; bi = a.bu; o = a.ou; K = 6; }
        else if (idx < 1920000)  { idx -= 1600000; X = a.Xp; W = a.Wp; bi = a.bp; o = a.op; K = 4; }
        else                     { idx -= 1920000; X = a.Xr; W = a.Wr; bi = a.br; o = a.orr; K = 3; }
        int r = idx >> 4, c0 = (idx & 15) * 8;
        float acc[8];
        {
            const float4 b0 = *(const float4*)(bi + c0);
            const float4 b1 = *(const float4*)(bi + c0 + 4);
            acc[0] = b0.x; acc[1] = b0.y; acc[2] = b0.z; acc[3] = b0.w;
            acc[4] = b1.x; acc[5] = b1.y; acc[6] = b1.z; acc[7] = b1.w;
        }
        for (int k = 0; k < K; ++k) {
            float xk = X[(size_t)r * K + k];
            const float4 w0 = *(const float4*)(W + k * 128 + c0);
            const float4 w1 = *(const float4*)(W + k * 128 + c0 + 4);
            acc[0] += xk * w0.x; acc[1] += xk * w0.y; acc[2] += xk * w0.z; acc[3] += xk * w0.w;
            acc[4] += xk * w1.x; acc[5] += xk * w1.y; acc[6] += xk * w1.z; acc[7] += xk * w1.w;
        }
        uint4 pk;
        pk.x = (unsigned)f2bf(acc[0]) | ((unsigned)f2bf(acc[1]) << 16);
        pk.y = (unsigned)f2bf(acc[2]) | ((unsigned)f2bf(acc[3]) << 16);
        pk.z = (unsigned)f2bf(acc[4]) | ((unsigned)f2bf(acc[5]) << 16);
        pk.w = (unsigned)f2bf(acc[6]) | ((unsigned)f2bf(acc[7]) << 16);
        *(uint4*)(o + (size_t)r * 128 + c0) = pk;
    }
}

// ---------------- gather mean over padded CSR (lean kernel: 0 LDS, high occupancy) --------
__device__ __forceinline__ void gm_row(
    const u16* __restrict__ feat, const int* __restrict__ cnt,
    const int* __restrict__ vals, int stride, u16* __restrict__ outp, int row, int lane)
{
    int deg = cnt[row];
    deg = __builtin_amdgcn_readfirstlane(deg);
    int n = deg < stride ? deg : stride;
    const int* vp = vals + row * stride;
    float a0 = 0.f, a1 = 0.f, b0 = 0.f, b1 = 0.f;
    float c0 = 0.f, c1 = 0.f, d0 = 0.f, d1 = 0.f;
    int j = 0;
    for (; j + 4 <= n; j += 4) {
        int i0 = __builtin_nontemporal_load(vp + j);
        int i1 = __builtin_nontemporal_load(vp + j + 1);
        int i2 = __builtin_nontemporal_load(vp + j + 2);
        int i3 = __builtin_nontemporal_load(vp + j + 3);
        unsigned u0 = *(const unsigned*)(feat + (size_t)i0 * 128 + lane * 2);
        unsigned u1 = *(const unsigned*)(feat + (size_t)i1 * 128 + lane * 2);
        unsigned u2 = *(const unsigned*)(feat + (size_t)i2 * 128 + lane * 2);
        unsigned u3 = *(const unsigned*)(feat + (size_t)i3 * 128 + lane * 2);
        a0 += bf2f((u16)(u0 & 0xffff)); a1 += bf2f((u16)(u0 >> 16));
        b0 += bf2f((u16)(u1 & 0xffff)); b1 += bf2f((u16)(u1 >> 16));
        c0 += bf2f((u16)(u2 & 0xffff)); c1 += bf2f((u16)(u2 >> 16));
        d0 += bf2f((u16)(u3 & 0xffff)); d1 += bf2f((u16)(u3 >> 16));
    }
    for (; j < n; ++j) {
        int i0 = __builtin_nontemporal_load(vp + j);
        unsigned u0 = *(const unsigned*)(feat + (size_t)i0 * 128 + lane * 2);
        a0 += bf2f((u16)(u0 & 0xffff)); a1 += bf2f((u16)(u0 >> 16));
    }
    float ax = (a0 + b0) + (c0 + d0), ay = (a1 + b1) + (c1 + d1);
    float inv = 1.0f / fmaxf((float)deg, 1.0f);
    unsigned o = (unsigned)f2bf(ax * inv) | ((unsigned)f2bf(ay * inv) << 16);
    *(unsigned*)(outp + (size_t)row * 128 + lane * 2) = o;
}

__global__ __launch_bounds__(256) void gather_mean2_kernel(
    const u16* __restrict__ feat,
    const int* __restrict__ cnt_pc, const int* __restrict__ val_pc, u16* __restrict__ out_pc,
    const int* __restrict__ cnt_url, const int* __restrict__ val_url, u16* __restrict__ out_url)
{
    int b = blockIdx.x;
    int lane = threadIdx.x & 63, w = threadIdx.x >> 6;
    if (b < 5000) gm_row(feat, cnt_pc, val_pc, S_UPD, out_pc, b * 4 + w, lane);
    else          gm_row(feat, cnt_url, val_url, S_UUD, out_url, (b - 5000) * 4 + w, lane);
}

// ---------------- fused 3-stage MFMA GEMM, double-buffered W + A prefetch ----------------
// mode 0: x1 = relu(mean@Wl0 + x0@Wr0 + b0)       [x1 -> LDS]
//         x2 = relu(mean@Wl1 + x1@Wr1 + b1 + x1)  [x2 -> LDS]
//         out = x2@Wc                             [-> global]
// mode 1: out = mean@Wl0 + b0
struct FSeg {
    const u16 *mean, *x0;
    const u16 *Wl0, *Wr0, *Wl1, *Wr1, *Wc;
    const float *b0, *b1;
    u16* out; int M; int bstart; int mode;
};
struct FArgs { FSeg s[3]; };

__global__ __launch_bounds__(256) void gemm_fused_kernel(FArgs fa)
{
    constexpr int XP = 136;                 // x_tile stride in u16
    __shared__ u16 Ws[2][128 * 40];         // 2 x 10 KB weight chunks (double buffer)
    __shared__ u16 Xs[128 * XP];            // 34 KB activation tile

    int si = 0;
    if ((int)blockIdx.x >= fa.s[1].bstart) si = 1;
    if ((int)blockIdx.x >= fa.s[2].bstart) si = 2;
    FSeg sg = fa.s[si];
    const int bb = blockIdx.x - sg.bstart;

    const int tid = threadIdx.x;
    const int wave = tid >> 6, lane = tid & 63;
    const int m = lane & 15, kq = lane >> 4;
    const int rloc = wave * 32;
    const int rbase = bb * 128 + rloc;
    const int sn = tid >> 1, spart = tid & 1;

    floatx4 acc[2][8];

    auto zeroAcc = [&]() {
#pragma unroll
        for (int mt = 0; mt < 2; ++mt)
#pragma unroll
            for (int nt = 0; nt < 8; ++nt) acc[mt][nt] = (floatx4)0.0f;
    };
    auto stageW = [&](const u16* Wt, int kc, int buf) {
        *(short8_t*)&Ws[buf][sn * 40 + spart * 16] =
            *(const short8_t*)(Wt + (size_t)sn * 128 + kc + spart * 16);
        *(short8_t*)&Ws[buf][sn * 40 + spart * 16 + 8] =
            *(const short8_t*)(Wt + (size_t)sn * 128 + kc + spart * 16 + 8);
    };
    auto loadAg = [&](const u16* A, int kc, int mt) -> short8_t {
        int row = rbase + mt * 16 + m; row = row < sg.M ? row : sg.M - 1;
        return *(const short8_t*)(A + (size_t)row * 128 + kc + kq * 8);
    };
    auto loadAs = [&](int kc, int mt) -> short8_t {
        return *(const short8_t*)&Xs[(rloc + mt * 16 + m) * XP + kc + kq * 8];
    };
    auto mfmaChunk = [&](short8_t a0, short8_t a1, int buf) {
#pragma unroll
        for (int nt = 0; nt < 8; ++nt) {
            short8_t b = *(const short8_t*)&Ws[buf][(nt * 16 + m) * 40 + kq * 8];
            acc[0][nt] = __builtin_amdgcn_mfma_f32_16x16x32_bf16(a0, b, acc[0][nt], 0, 0, 0);
            acc[1][nt] = __builtin_amdgcn_mfma_f32_16x16x32_bf16(a1, b, acc[1][nt], 0, 0, 0);
        }
    };
    auto passDual = [&](const u16* W1, const u16* A1g, const u16* W2, const u16* A2g, bool a2lds) {
        zeroAcc();
        stageW(W1, 0, 0);
        short8_t an0 = loadAg(A1g, 0, 0), an1 = loadAg(A1g, 0, 1);
        __syncthreads();
        for (int c = 0; c < 8; ++c) {
            int c1 = c + 1;
            if (c1 < 8) {
                int kc1 = (c1 & 3) * 32;
                stageW(c1 < 4 ? W1 : W2, kc1, c1 & 1);
            }
            short8_t a0 = an0, a1 = an1;
            if (c1 < 8) {
                int kc1 = (c1 & 3) * 32;
                if (c1 < 4)     { an0 = loadAg(A1g, kc1, 0); an1 = loadAg(A1g, kc1, 1); }
                else if (a2lds) { an0 = loadAs(kc1, 0);      an1 = loadAs(kc1, 1); }
                else            { an0 = loadAg(A2g, kc1, 0); an1 = loadAg(A2g, kc1, 1); }
            }
            mfmaChunk(a0, a1, c & 1);
            __syncthreads();
        }
    };
    auto passSingle = [&](const u16* W1, const u16* A1g, bool lds) {
        zeroAcc();
        stageW(W1, 0, 0);
        short8_t an0, an1;
        if (lds) { an0 = loadAs(0, 0); an1 = loadAs(0, 1); }
        else     { an0 = loadAg(A1g, 0, 0); an1 = loadAg(A1g, 0, 1); }
        __syncthreads();
        for (int c = 0; c < 4; ++c) {
            int c1 = c + 1;
            if (c1 < 4) stageW(W1, c1 * 32, c1 & 1);
            short8_t a0 = an0, a1 = an1;
            if (c1 < 4) {
                if (lds) { an0 = loadAs(c1 * 32, 0); an1 = loadAs(c1 * 32, 1); }
                else     { an0 = loadAg(A1g, c1 * 32, 0); an1 = loadAg(A1g, c1 * 32, 1); }
            }
            mfmaChunk(a0, a1, c & 1);
            __syncthreads();
        }
    };
    // C/D layout: col = lane&15, row = (lane>>4)*4 + r; wave epilogues touch only their
    // own 32-row band (same band as their A-frag LDS reads) -> no cross-wave hazard.
    auto epilogueToLds = [&](const float* bias, bool addRes) {
#pragma unroll
        for (int nt = 0; nt < 8; ++nt) {
            int col = nt * 16 + m;
            float bv = bias[col];
#pragma unroll
            for (int mt = 0; mt < 2; ++mt)
#pragma unroll
                for (int r = 0; r < 4; ++r) {
                    int lrow = rloc + mt * 16 + kq * 4 + r;
                    float v = acc[mt][nt][r] + bv;
                    if (addRes) v += bf2f(Xs[lrow * XP + col]);
                    Xs[lrow * XP + col] = f2bf(fmaxf(v, 0.f));
                }
        }
        __syncthreads();   // order LDS epilogue writes before next pass's cross-lane reads
    };
    auto epilogueToGlobal = [&](const float* bias, u16* outp) {
#pragma unroll
        for (int nt = 0; nt < 8; ++nt) {
            int col = nt * 16 + m;
            float bv = bias ? bias[col] : 0.0f;
#pragma unroll
            for (int mt = 0; mt < 2; ++mt)
#pragma unroll
                for (int r = 0; r < 4; ++r) {
                    int row = rbase + mt * 16 + kq * 4 + r;
                    if (row < sg.M) outp[(size_t)row * 128 + col] = f2bf(acc[mt][nt][r] + bv);
                }
        }
    };

    if (sg.mode == 0) {
        passDual(sg.Wl0, sg.mean, sg.Wr0, sg.x0, false);
        epilogueToLds(sg.b0, false);
        passDual(sg.Wl1, sg.mean, sg.Wr1, nullptr, true);
        epilogueToLds(sg.b1, true);
        passSingle(sg.Wc, nullptr, true);
        epilogueToGlobal(nullptr, sg.out);
    } else {
        passSingle(sg.Wl0, sg.mean, false);
        epilogueToGlobal(sg.b0, sg.out);
    }
}

// ---------------- fused ctx-gather + classifier: enr read once, h never in global ----------
// Block = 64 user rows; wave owns 16. Phase A: gather-accumulate enr rows in fp32
// registers, write bf16 to LDS Xs. __syncthreads. Phase B: MFMA classifier + reduce.
// (Correctness incl. graph replay verified in R12.)
__global__ __launch_bounds__(256) void ctx_final_kernel(
    const u16* __restrict__ enr,
    const int* __restrict__ cnt_up, const u16* __restrict__ val_up, const u16* __restrict__ pcW,
    const int* __restrict__ cnt_uu, const u16* __restrict__ val_uu, const u16* __restrict__ urlW,
    const u16* __restrict__ Wc1_t, const float* __restrict__ bc1,
    const float* __restrict__ Wc2, const float* __restrict__ bc2,
    float* __restrict__ out, int M)
{
    __shared__ u16 Xs[64 * 136];               // 17.4 KB enr' tile (bf16)
    __shared__ u16 Wc1s[64 * 136];             // 17.4 KB Wc1 [n][k]

    const int tid = threadIdx.x;
    const int wave = tid >> 6, lane = tid & 63;
    const int m = lane & 15, kq = lane >> 4;
    const int rbw = blockIdx.x * 64 + wave * 16;

    // stage Wc1 (ordered before phase-B reads by the phase A/B barrier)
    for (int idx = tid; idx < 64 * 16; idx += 256) {
        int row = idx >> 4, part = idx & 15;
        *(short8_t*)&Wc1s[row * 136 + part * 8] =
            *(const short8_t*)(Wc1_t + (size_t)row * 128 + part * 8);
    }

    // ---- phase A: enr' rows -> Xs (each wave writes only its own 16-row band) ----
    for (int rr = 0; rr < 16; ++rr) {
        int row = rbw + rr;
        int lrow = wave * 16 + rr;
        unsigned o = 0;
        if (row < M) {
            int n0 = cnt_up[row], n1 = cnt_uu[row];
            n0 = __builtin_amdgcn_readfirstlane(n0); n1 = __builtin_amdgcn_readfirstlane(n1);
            n0 = n0 < S_SRC ? n0 : S_SRC; n1 = n1 < S_SRC ? n1 : S_SRC;
            int total = n0 + n1;
            const u16* vu = val_up + row * S_SRC;
            const u16* vr = val_uu + row * S_SRC;
            unsigned eu = *(const unsigned*)(enr + (size_t)row * 128 + lane * 2);
            float a0 = bf2f((u16)(eu & 0xffff)), a1 = bf2f((u16)(eu >> 16));
            float b0 = 0.f, b1 = 0.f, c0 = 0.f, c1 = 0.f, d0 = 0.f, d1 = 0.f;
            auto ld = [&](int t) -> unsigned {
                bool isup = t < n0;
                int idx = isup ? vu[t] : vr[t - n0];
                const u16* base = isup ? pcW : urlW;
                return *(const unsigned*)(base + (size_t)idx * 128 + lane * 2);
            };
            int t = 0;
            for (; t + 4 <= total; t += 4) {
                unsigned u0 = ld(t + 0), u1 = ld(t + 1), u2 = ld(t + 2), u3 = ld(t + 3);
                a0 += bf2f((u16)(u0 & 0xffff)); a1 += bf2f((u16)(u0 >> 16));
                b0 += bf2f((u16)(u1 & 0xffff)); b1 += bf2f((u16)(u1 >> 16));
                c0 += bf2f((u16)(u2 & 0xffff)); c1 += bf2f((u16)(u2 >> 16));
                d0 += bf2f((u16)(u3 & 0xffff)); d1 += bf2f((u16)(u3 >> 16));
            }
            for (; t < total; ++t) {
                unsigned u0 = ld(t);
                a0 += bf2f((u16)(u0 & 0xffff)); a1 += bf2f((u16)(u0 >> 16));
            }
            float ax = (a0 + b0) + (c0 + d0), ay = (a1 + b1) + (c1 + d1);
            o = (unsigned)f2bf(ax) | ((unsigned)f2bf(ay) << 16);
        }
        *(unsigned*)&Xs[lrow * 136 + 2 * lane] = o;
    }

    __syncthreads();   // LDS producer->consumer boundary (cross-lane)

    // ---- phase B: h = relu(Xs@Wc1 + bc1); out = h@Wc2 + bc2 ----
    floatx4 acc2[4];
#pragma unroll
    for (int nt = 0; nt < 4; ++nt) acc2[nt] = (floatx4)0.0f;
    for (int c = 0; c < 4; ++c) {
        int kc = c * 32;
        short8_t a = *(const short8_t*)&Xs[(wave * 16 + m) * 136 + kc + kq * 8];
#pragma unroll
        for (int nt = 0; nt < 4; ++nt) {
            short8_t b = *(const short8_t*)&Wc1s[(nt * 16 + m) * 136 + kc + kq * 8];
            acc2[nt] = __builtin_amdgcn_mfma_f32_16x16x32_bf16(a, b, acc2[nt], 0, 0, 0);
        }
    }

    float w0v[4], w1v[4], bv[4];
#pragma unroll
    for (int nt = 0; nt < 4; ++nt) {
        int col = nt * 16 + m;
        w0v[nt] = Wc2[col * 2 + 0];
        w1v[nt] = Wc2[col * 2 + 1];
        bv[nt]  = bc1[col];
    }
    float b20 = bc2[0], b21 = bc2[1];
#pragma unroll
    for (int r = 0; r < 4; ++r) {
        float o0 = 0.f, o1 = 0.f;
#pragma unroll
        for (int nt = 0; nt < 4; ++nt) {
            float v = acc2[nt][r] + bv[nt];
            v = fmaxf(v, 0.f);
            o0 += v * w0v[nt];
            o1 += v * w1v[nt];
        }
#pragma unroll
        for (int off = 1; off < 16; off <<= 1) {
            o0 += __shfl_xor(o0, off, 64);
            o1 += __shfl_xor(o1, off, 64);
        }
        if (m == 0) {
            int row = rbw + kq * 4 + r;
            if (row < M) {
                out[(size_t)row * 2 + 0] = o0 + b20;
                out[(size_t)row * 2 + 1] = o1 + b21;
            }
        }
    }
}

extern "C" void kernel_launch(void* const* d_in, const int* in_sizes, int n_in,
                              void* d_out, int out_size, void* d_ws, size_t ws_size,
                              hipStream_t stream)
{
    const float* x_user  = (const float*)d_in[0];
    const float* x_pc    = (const float*)d_in[1];
    const float* x_url   = (const float*)d_in[2];
    const int* e_up_src  = (const int*)d_in[3];
    const int* e_up_dst  = (const int*)d_in[4];
    const int* e_uu_src  = (const int*)d_in[5];
    const int* e_uu_dst  = (const int*)d_in[6];
    const float* Wu      = (const float*)d_in[7];
    const float* bu      = (const float*)d_in[8];
    const float* Wp      = (const float*)d_in[9];
    const float* bp      = (const float*)d_in[10];
    const float* Wr_feat = (const float*)d_in[11];
    const float* br_feat = (const float*)d_in[12];
    const float* Wl_pc   = (const float*)d_in[13];
    const float* bl_pc   = (const float*)d_in[14];
    const float* Wr_pc   = (const float*)d_in[15];
    const float* Wl_url  = (const float*)d_in[16];
    const float* bl_url  = (const float*)d_in[17];
    const float* Wr_url  = (const float*)d_in[18];
    const float* Wctx    = (const float*)d_in[19];
    const float* bctx    = (const float*)d_in[20];
    const float* Wc1     = (const float*)d_in[21];
    const float* bc1     = (const float*)d_in[22];
    const float* Wc2     = (const float*)d_in[23];
    const float* bc2     = (const float*)d_in[24];
    float* out = (float*)d_out;

    // ---- workspace layout (4-byte words) ----
    char* wsb = (char*)d_ws;
    u16* user_bf  = (u16*)(wsb);                            //  6,400,000 w
    u16* enr      = (u16*)(wsb + 4ull *  6400000);          //  6,400,000 w
    u16* mean_pc  = (u16*)(wsb + 4ull * 12800000);          //  1,280,000 w
    u16* mean_url = (u16*)(wsb + 4ull * 14080000);          //  3,200,000 w
    u16* pc_a     = (u16*)(wsb + 4ull * 17280000);          //  1,280,000 w
    u16* pc_b     = (u16*)(wsb + 4ull * 18560000);          //  1,280,000 w
    u16* url_a    = (u16*)(wsb + 4ull * 19840000);          //  3,200,000 w
    u16* url_b    = (u16*)(wsb + 4ull * 23040000);          //  3,200,000 w
    u16* Wt       = (u16*)(wsb + 4ull * 26240000);          //    100,000 w slot
    int* cnts     = (int*)(wsb + 4ull * 26340000);          //    270,000 w (4 count arrays)
    int* up_dst_val = (int*)(wsb + 4ull * 26610000);        //    960,000 w (20000*48)
    int* uu_dst_val = (int*)(wsb + 4ull * 27570000);        //  2,000,000 w (50000*40)
    u16* up_src_val = (u16*)(wsb + 4ull * 29570000);        //  1,200,000 w (100000*24 u16)
    u16* uu_src_val = (u16*)(wsb + 4ull * 30770000);        //  1,200,000 w

    int* cnt_up_dst = cnts + 0;
    int* cnt_uu_dst = cnts + 20000;
    int* cnt_up_src = cnts + 70000;
    int* cnt_uu_src = cnts + 170000;

    const int T = 256;

    // 0. zero CSR counters
    hipMemsetAsync(cnts, 0, 270000ull * 4, stream);

    // 1. merged prep+fill: fill (1960, first) | wcvt (768) | proj3 (10625)
    PFArgs pf;
    pf.wsrc[0] = Wl_pc;               pf.wsrc[1] = Wr_pc;
    pf.wsrc[2] = Wl_pc + 128 * 128;   pf.wsrc[3] = Wr_pc + 128 * 128;
    pf.wsrc[4] = Wl_url;              pf.wsrc[5] = Wr_url;
    pf.wsrc[6] = Wl_url + 128 * 128;  pf.wsrc[7] = Wr_url + 128 * 128;
    pf.wsrc[8] = Wctx;                pf.wsrc[9] = Wctx + 128 * 128;
    pf.wsrc[10] = Wctx + 256 * 128;   pf.wsrc[11] = Wc1;
    pf.wdst = Wt;
    pf.Xu = x_user; pf.Wu = Wu;      pf.bu = bu;      pf.ou = user_bf;
    pf.Xp = x_pc;   pf.Wp = Wp;      pf.bp = bp;      pf.op = pc_a;
    pf.Xr = x_url;  pf.Wr = Wr_feat; pf.br = br_feat; pf.orr = url_a;
    pf.up_src = e_up_src; pf.up_dst = e_up_dst;
    pf.uu_src = e_uu_src; pf.uu_dst = e_uu_dst;
    pf.cnt_up_dst = cnt_up_dst; pf.cnt_uu_dst = cnt_uu_dst;
    pf.cnt_up_src = cnt_up_src; pf.cnt_uu_src = cnt_uu_src;
    pf.val_up_dst = up_dst_val; pf.val_uu_dst = uu_dst_val;
    pf.val_up_src = up_src_val; pf.val_uu_src = uu_src_val;
    prepfill_kernel<<<1960 + 768 + 10625, T, 0, stream>>>(pf);

    // 2. mean aggregation of user into pc/url (lean standalone kernel)
    gather_mean2_kernel<<<5000 + 12500, T, 0, stream>>>(
        user_bf, cnt_up_dst, up_dst_val, mean_pc, cnt_uu_dst, uu_dst_val, mean_url);

    // 3. fused GEMMs: pc chain | url chain | user@Wctx  (one dispatch)
    FArgs fg;
    fg.s[0] = { mean_pc,  pc_a,  Wt + 0 * 16384, Wt + 1 * 16384, Wt + 2 * 16384, Wt + 3 * 16384,
                Wt + 9 * 16384,  bl_pc,  bl_pc + 128,  pc_b,  N_PC_C,   0,   0 };
    fg.s[1] = { mean_url, url_a, Wt + 4 * 16384, Wt + 5 * 16384, Wt + 6 * 16384, Wt + 7 * 16384,
                Wt + 10 * 16384, bl_url, bl_url + 128, url_b, N_URL_C,  157, 0 };
    fg.s[2] = { user_bf,  nullptr, Wt + 8 * 16384, nullptr, nullptr, nullptr,
                nullptr,         bctx,   nullptr,      enr,   N_USER_C, 548, 1 };
    gemm_fused_kernel<<<548 + 782, T, 0, stream>>>(fg);

    // 4. fused ctx-gather + classifier
    ctx_final_kernel<<<(N_USER_C + 63) / 64, T, 0, stream>>>(
        enr, cnt_up_src, up_src_val, pc_b, cnt_uu_src, uu_src_val, url_b,
        Wt + 11 * 16384, bc1, Wc2, bc2, out, N_USER_C);
}

// Round 14
// 345.837 us; speedup vs baseline: 1.2523x; 1.0810x over previous
//
#include <hip/hip_runtime.h>

typedef unsigned short u16;
typedef short short8_t __attribute__((ext_vector_type(8)));
typedef float floatx4 __attribute__((ext_vector_type(4)));

static constexpr int N_USER_C = 100000;
static constexpr int N_PC_C   = 20000;
static constexpr int N_URL_C  = 50000;
static constexpr int E_UP_C   = 250000;
static constexpr int E_UU_C   = 500000;

// padded-CSR strides (Poisson degree tails: overflow prob negligible at these bounds)
static constexpr int S_UPD = 48;   // up_dst mean 12.5
static constexpr int S_UUD = 40;   // uu_dst mean 10
static constexpr int S_SRC = 24;   // up_src mean 2.5 / uu_src mean 5

__device__ __forceinline__ float bf2f(u16 h) {
    return __uint_as_float(((unsigned)h) << 16);
}
__device__ __forceinline__ u16 f2bf(float f) {
    unsigned u = __float_as_uint(f);
    u += 0x7fffu + ((u >> 16) & 1u);
    return (u16)(u >> 16);
}

// ---------------- merged prep+fill: fill (1960) | wcvt (768) | proj3 (10625) ----------------
// Both paths lean (8-16 VGPR, 0 LDS) -> safe heterogeneous merge (R12/R13 lesson: never
// tax latency-bound work with a fat-footprint kernel).
struct PFArgs {
    const float* wsrc[12];
    u16* wdst;
    const float *Xu, *Wu, *bu, *Xp, *Wp, *bp, *Xr, *Wr, *br;
    u16 *ou, *op, *orr;
    const int *up_src, *up_dst, *uu_src, *uu_dst;
    int *cnt_up_dst, *cnt_uu_dst, *cnt_up_src, *cnt_uu_src;
    int *val_up_dst, *val_uu_dst;
    u16 *val_up_src, *val_uu_src;
};
__global__ __launch_bounds__(256) void prepfill_kernel(PFArgs a)
{
    int b = blockIdx.x, tid = threadIdx.x;
    if (b < 1960) {
        const int range = b & 7;
        const int ebase = (b >> 3) * 2048 + tid;
#pragma unroll
        for (int i = 0; i < 8; ++i) {
            int e = ebase + i * 256;
            if (e < E_UP_C) {
                int s = __builtin_nontemporal_load(a.up_src + e);
                int d = __builtin_nontemporal_load(a.up_dst + e);
                if (d / 2500 == range) {
                    int p = atomicAdd(&a.cnt_up_dst[d], 1);
                    if (p < S_UPD) a.val_up_dst[d * S_UPD + p] = s;
                }
                if (s / 12500 == range) {
                    int p = atomicAdd(&a.cnt_up_src[s], 1);
                    if (p < S_SRC) a.val_up_src[s * S_SRC + p] = (u16)d;
                }
            }
            if (e < E_UU_C) {
                int s = __builtin_nontemporal_load(a.uu_src + e);
                int d = __builtin_nontemporal_load(a.uu_dst + e);
                if (d / 6250 == range) {
                    int p = atomicAdd(&a.cnt_uu_dst[d], 1);
                    if (p < S_UUD) a.val_uu_dst[d * S_UUD + p] = s;
                }
                if (s / 12500 == range) {
                    int p = atomicAdd(&a.cnt_uu_src[s], 1);
                    if (p < S_SRC) a.val_uu_src[s * S_SRC + p] = (u16)d;
                }
            }
        }
    } else if (b < 1960 + 768) {
        int idx = (b - 1960) * 256 + tid;
        int m = idx >> 14, e = idx & 16383;
        int n = e >> 7, k = e & 127;
        int Nm = (m == 11) ? 64 : 128;
        u16 v = 0;
        if (n < Nm) v = f2bf(a.wsrc[m][k * Nm + n]);
        a.wdst[(size_t)m * 16384 + n * 128 + k] = v;
    } else {
        int idx = (b - 1960 - 768) * 256 + tid;
        const float* X; const float* W; const float* bi; u16* o; int K;
        if (idx < 1600000)       { X = a.Xu; W = a.Wu; bi = a.bu; o = a.ou; K = 6; }
        else if (idx < 1920000)  { idx -= 1600000; X = a.Xp; W = a.Wp; bi = a.bp; o = a.op; K = 4; }
        else                     { idx -= 1920000; X = a.Xr; W = a.Wr; bi = a.br; o = a.orr; K = 3; }
        int r = idx >> 4, c0 = (idx & 15) * 8;
        float acc[8];
        {
            const float4 b0 = *(const float4*)(bi + c0);
            const float4 b1 = *(const float4*)(bi + c0 + 4);
            acc[0] = b0.x; acc[1] = b0.y; acc[2] = b0.z; acc[3] = b0.w;
            acc[4] = b1.x; acc[5] = b1.y; acc[6] = b1.z; acc[7] = b1.w;
        }
        for (int k = 0; k < K; ++k) {
            float xk = X[(size_t)r * K + k];
            const float4 w0 = *(const float4*)(W + k * 128 + c0);
            const float4 w1 = *(const float4*)(W + k * 128 + c0 + 4);
            acc[0] += xk * w0.x; acc[1] += xk * w0.y; acc[2] += xk * w0.z; acc[3] += xk * w0.w;
            acc[4] += xk * w1.x; acc[5] += xk * w1.y; acc[6] += xk * w1.z; acc[7] += xk * w1.w;
        }
        uint4 pk;
        pk.x = (unsigned)f2bf(acc[0]) | ((unsigned)f2bf(acc[1]) << 16);
        pk.y = (unsigned)f2bf(acc[2]) | ((unsigned)f2bf(acc[3]) << 16);
        pk.z = (unsigned)f2bf(acc[4]) | ((unsigned)f2bf(acc[5]) << 16);
        pk.w = (unsigned)f2bf(acc[6]) | ((unsigned)f2bf(acc[7]) << 16);
        *(uint4*)(o + (size_t)r * 128 + c0) = pk;
    }
}

// ---------------- gather mean over padded CSR (lean kernel: 0 LDS, high occupancy) --------
__device__ __forceinline__ void gm_row(
    const u16* __restrict__ feat, const int* __restrict__ cnt,
    const int* __restrict__ vals, int stride, u16* __restrict__ outp, int row, int lane)
{
    int deg = cnt[row];
    deg = __builtin_amdgcn_readfirstlane(deg);
    int n = deg < stride ? deg : stride;
    const int* vp = vals + row * stride;
    float a0 = 0.f, a1 = 0.f, b0 = 0.f, b1 = 0.f;
    float c0 = 0.f, c1 = 0.f, d0 = 0.f, d1 = 0.f;
    int j = 0;
    for (; j + 4 <= n; j += 4) {
        int i0 = __builtin_nontemporal_load(vp + j);
        int i1 = __builtin_nontemporal_load(vp + j + 1);
        int i2 = __builtin_nontemporal_load(vp + j + 2);
        int i3 = __builtin_nontemporal_load(vp + j + 3);
        unsigned u0 = *(const unsigned*)(feat + (size_t)i0 * 128 + lane * 2);
        unsigned u1 = *(const unsigned*)(feat + (size_t)i1 * 128 + lane * 2);
        unsigned u2 = *(const unsigned*)(feat + (size_t)i2 * 128 + lane * 2);
        unsigned u3 = *(const unsigned*)(feat + (size_t)i3 * 128 + lane * 2);
        a0 += bf2f((u16)(u0 & 0xffff)); a1 += bf2f((u16)(u0 >> 16));
        b0 += bf2f((u16)(u1 & 0xffff)); b1 += bf2f((u16)(u1 >> 16));
        c0 += bf2f((u16)(u2 & 0xffff)); c1 += bf2f((u16)(u2 >> 16));
        d0 += bf2f((u16)(u3 & 0xffff)); d1 += bf2f((u16)(u3 >> 16));
    }
    for (; j < n; ++j) {
        int i0 = __builtin_nontemporal_load(vp + j);
        unsigned u0 = *(const unsigned*)(feat + (size_t)i0 * 128 + lane * 2);
        a0 += bf2f((u16)(u0 & 0xffff)); a1 += bf2f((u16)(u0 >> 16));
    }
    float ax = (a0 + b0) + (c0 + d0), ay = (a1 + b1) + (c1 + d1);
    float inv = 1.0f / fmaxf((float)deg, 1.0f);
    unsigned o = (unsigned)f2bf(ax * inv) | ((unsigned)f2bf(ay * inv) << 16);
    *(unsigned*)(outp + (size_t)row * 128 + lane * 2) = o;
}

__global__ __launch_bounds__(256) void gather_mean2_kernel(
    const u16* __restrict__ feat,
    const int* __restrict__ cnt_pc, const int* __restrict__ val_pc, u16* __restrict__ out_pc,
    const int* __restrict__ cnt_url, const int* __restrict__ val_url, u16* __restrict__ out_url)
{
    int b = blockIdx.x;
    int lane = threadIdx.x & 63, w = threadIdx.x >> 6;
    if (b < 5000) gm_row(feat, cnt_pc, val_pc, S_UPD, out_pc, b * 4 + w, lane);
    else          gm_row(feat, cnt_url, val_url, S_UUD, out_url, (b - 5000) * 4 + w, lane);
}

// ---------------- fused 3-stage MFMA GEMM, double-buffered W + A prefetch ----------------
// mode 0: x1 = relu(mean@Wl0 + x0@Wr0 + b0)       [x1 -> LDS]
//         x2 = relu(mean@Wl1 + x1@Wr1 + b1 + x1)  [x2 -> LDS]
//         out = x2@Wc                             [-> global]
// mode 1: out = mean@Wl0 + b0
struct FSeg {
    const u16 *mean, *x0;
    const u16 *Wl0, *Wr0, *Wl1, *Wr1, *Wc;
    const float *b0, *b1;
    u16* out; int M; int bstart; int mode;
};
struct FArgs { FSeg s[3]; };

__global__ __launch_bounds__(256) void gemm_fused_kernel(FArgs fa)
{
    constexpr int XP = 136;                 // x_tile stride in u16
    __shared__ u16 Ws[2][128 * 40];         // 2 x 10 KB weight chunks (double buffer)
    __shared__ u16 Xs[128 * XP];            // 34 KB activation tile

    int si = 0;
    if ((int)blockIdx.x >= fa.s[1].bstart) si = 1;
    if ((int)blockIdx.x >= fa.s[2].bstart) si = 2;
    FSeg sg = fa.s[si];
    const int bb = blockIdx.x - sg.bstart;

    const int tid = threadIdx.x;
    const int wave = tid >> 6, lane = tid & 63;
    const int m = lane & 15, kq = lane >> 4;
    const int rloc = wave * 32;
    const int rbase = bb * 128 + rloc;
    const int sn = tid >> 1, spart = tid & 1;

    floatx4 acc[2][8];

    auto zeroAcc = [&]() {
#pragma unroll
        for (int mt = 0; mt < 2; ++mt)
#pragma unroll
            for (int nt = 0; nt < 8; ++nt) acc[mt][nt] = (floatx4)0.0f;
    };
    auto stageW = [&](const u16* Wt, int kc, int buf) {
        *(short8_t*)&Ws[buf][sn * 40 + spart * 16] =
            *(const short8_t*)(Wt + (size_t)sn * 128 + kc + spart * 16);
        *(short8_t*)&Ws[buf][sn * 40 + spart * 16 + 8] =
            *(const short8_t*)(Wt + (size_t)sn * 128 + kc + spart * 16 + 8);
    };
    auto loadAg = [&](const u16* A, int kc, int mt) -> short8_t {
        int row = rbase + mt * 16 + m; row = row < sg.M ? row : sg.M - 1;
        return *(const short8_t*)(A + (size_t)row * 128 + kc + kq * 8);
    };
    auto loadAs = [&](int kc, int mt) -> short8_t {
        return *(const short8_t*)&Xs[(rloc + mt * 16 + m) * XP + kc + kq * 8];
    };
    auto mfmaChunk = [&](short8_t a0, short8_t a1, int buf) {
#pragma unroll
        for (int nt = 0; nt < 8; ++nt) {
            short8_t b = *(const short8_t*)&Ws[buf][(nt * 16 + m) * 40 + kq * 8];
            acc[0][nt] = __builtin_amdgcn_mfma_f32_16x16x32_bf16(a0, b, acc[0][nt], 0, 0, 0);
            acc[1][nt] = __builtin_amdgcn_mfma_f32_16x16x32_bf16(a1, b, acc[1][nt], 0, 0, 0);
        }
    };
    auto passDual = [&](const u16* W1, const u16* A1g, const u16* W2, const u16* A2g, bool a2lds) {
        zeroAcc();
        stageW(W1, 0, 0);
        short8_t an0 = loadAg(A1g, 0, 0), an1 = loadAg(A1g, 0, 1);
        __syncthreads();
        for (int c = 0; c < 8; ++c) {
            int c1 = c + 1;
            if (c1 < 8) {
                int kc1 = (c1 & 3) * 32;
                stageW(c1 < 4 ? W1 : W2, kc1, c1 & 1);
            }
            short8_t a0 = an0, a1 = an1;
            if (c1 < 8) {
                int kc1 = (c1 & 3) * 32;
                if (c1 < 4)     { an0 = loadAg(A1g, kc1, 0); an1 = loadAg(A1g, kc1, 1); }
                else if (a2lds) { an0 = loadAs(kc1, 0);      an1 = loadAs(kc1, 1); }
                else            { an0 = loadAg(A2g, kc1, 0); an1 = loadAg(A2g, kc1, 1); }
            }
            mfmaChunk(a0, a1, c & 1);
            __syncthreads();
        }
    };
    auto passSingle = [&](const u16* W1, const u16* A1g, bool lds) {
        zeroAcc();
        stageW(W1, 0, 0);
        short8_t an0, an1;
        if (lds) { an0 = loadAs(0, 0); an1 = loadAs(0, 1); }
        else     { an0 = loadAg(A1g, 0, 0); an1 = loadAg(A1g, 0, 1); }
        __syncthreads();
        for (int c = 0; c < 4; ++c) {
            int c1 = c + 1;
            if (c1 < 4) stageW(W1, c1 * 32, c1 & 1);
            short8_t a0 = an0, a1 = an1;
            if (c1 < 4) {
                if (lds) { an0 = loadAs(c1 * 32, 0); an1 = loadAs(c1 * 32, 1); }
                else     { an0 = loadAg(A1g, c1 * 32, 0); an1 = loadAg(A1g, c1 * 32, 1); }
            }
            mfmaChunk(a0, a1, c & 1);
            __syncthreads();
        }
    };
    // C/D layout: col = lane&15, row = (lane>>4)*4 + r; wave epilogues touch only their
    // own 32-row band (same band as their A-frag LDS reads) -> no cross-wave hazard.
    auto epilogueToLds = [&](const float* bias, bool addRes) {
#pragma unroll
        for (int nt = 0; nt < 8; ++nt) {
            int col = nt * 16 + m;
            float bv = bias[col];
#pragma unroll
            for (int mt = 0; mt < 2; ++mt)
#pragma unroll
                for (int r = 0; r < 4; ++r) {
                    int lrow = rloc + mt * 16 + kq * 4 + r;
                    float v = acc[mt][nt][r] + bv;
                    if (addRes) v += bf2f(Xs[lrow * XP + col]);
                    Xs[lrow * XP + col] = f2bf(fmaxf(v, 0.f));
                }
        }
        __syncthreads();   // order LDS epilogue writes before next pass's cross-lane reads
    };
    auto epilogueToGlobal = [&](const float* bias, u16* outp) {
#pragma unroll
        for (int nt = 0; nt < 8; ++nt) {
            int col = nt * 16 + m;
            float bv = bias ? bias[col] : 0.0f;
#pragma unroll
            for (int mt = 0; mt < 2; ++mt)
#pragma unroll
                for (int r = 0; r < 4; ++r) {
                    int row = rbase + mt * 16 + kq * 4 + r;
                    if (row < sg.M) outp[(size_t)row * 128 + col] = f2bf(acc[mt][nt][r] + bv);
                }
        }
    };

    if (sg.mode == 0) {
        passDual(sg.Wl0, sg.mean, sg.Wr0, sg.x0, false);
        epilogueToLds(sg.b0, false);
        passDual(sg.Wl1, sg.mean, sg.Wr1, nullptr, true);
        epilogueToLds(sg.b1, true);
        passSingle(sg.Wc, nullptr, true);
        epilogueToGlobal(nullptr, sg.out);
    } else {
        passSingle(sg.Wl0, sg.mean, false);
        epilogueToGlobal(sg.b0, sg.out);
    }
}

// ---------------- fused ctx-gather + classifier (lean: Xs only, Wc1 read from L2) --------
// Block = 64 user rows; wave owns 16. Phase A: gather-accumulate enr rows in fp32
// registers, write bf16 to LDS Xs. __syncthreads. Phase B: MFMA classifier with
// B-fragments loaded directly from global (Wc1 is 16 KB, shared by all blocks -> L2-hot).
// LDS 17.4 KB -> 8 blocks/CU = full 32 waves/CU for the latency-bound gather (R13 fix).
__global__ __launch_bounds__(256) void ctx_final_kernel(
    const u16* __restrict__ enr,
    const int* __restrict__ cnt_up, const u16* __restrict__ val_up, const u16* __restrict__ pcW,
    const int* __restrict__ cnt_uu, const u16* __restrict__ val_uu, const u16* __restrict__ urlW,
    const u16* __restrict__ Wc1_t, const float* __restrict__ bc1,
    const float* __restrict__ Wc2, const float* __restrict__ bc2,
    float* __restrict__ out, int M)
{
    __shared__ u16 Xs[64 * 136];               // 17.4 KB enr' tile (bf16)

    const int tid = threadIdx.x;
    const int wave = tid >> 6, lane = tid & 63;
    const int m = lane & 15, kq = lane >> 4;
    const int rbw = blockIdx.x * 64 + wave * 16;

    // ---- phase A: enr' rows -> Xs (each wave writes only its own 16-row band) ----
    for (int rr = 0; rr < 16; ++rr) {
        int row = rbw + rr;
        int lrow = wave * 16 + rr;
        unsigned o = 0;
        if (row < M) {
            int n0 = cnt_up[row], n1 = cnt_uu[row];
            n0 = __builtin_amdgcn_readfirstlane(n0); n1 = __builtin_amdgcn_readfirstlane(n1);
            n0 = n0 < S_SRC ? n0 : S_SRC; n1 = n1 < S_SRC ? n1 : S_SRC;
            int total = n0 + n1;
            const u16* vu = val_up + row * S_SRC;
            const u16* vr = val_uu + row * S_SRC;
            unsigned eu = *(const unsigned*)(enr + (size_t)row * 128 + lane * 2);
            float a0 = bf2f((u16)(eu & 0xffff)), a1 = bf2f((u16)(eu >> 16));
            float b0 = 0.f, b1 = 0.f, c0 = 0.f, c1 = 0.f, d0 = 0.f, d1 = 0.f;
            auto ld = [&](int t) -> unsigned {
                bool isup = t < n0;
                int idx = isup ? vu[t] : vr[t - n0];
                const u16* base = isup ? pcW : urlW;
                return *(const unsigned*)(base + (size_t)idx * 128 + lane * 2);
            };
            int t = 0;
            for (; t + 4 <= total; t += 4) {
                unsigned u0 = ld(t + 0), u1 = ld(t + 1), u2 = ld(t + 2), u3 = ld(t + 3);
                a0 += bf2f((u16)(u0 & 0xffff)); a1 += bf2f((u16)(u0 >> 16));
                b0 += bf2f((u16)(u1 & 0xffff)); b1 += bf2f((u16)(u1 >> 16));
                c0 += bf2f((u16)(u2 & 0xffff)); c1 += bf2f((u16)(u2 >> 16));
                d0 += bf2f((u16)(u3 & 0xffff)); d1 += bf2f((u16)(u3 >> 16));
            }
            for (; t < total; ++t) {
                unsigned u0 = ld(t);
                a0 += bf2f((u16)(u0 & 0xffff)); a1 += bf2f((u16)(u0 >> 16));
            }
            float ax = (a0 + b0) + (c0 + d0), ay = (a1 + b1) + (c1 + d1);
            o = (unsigned)f2bf(ax) | ((unsigned)f2bf(ay) << 16);
        }
        *(unsigned*)&Xs[lrow * 136 + 2 * lane] = o;
    }

    __syncthreads();   // LDS producer->consumer boundary (cross-lane)

    // ---- phase B: h = relu(Xs@Wc1 + bc1); out = h@Wc2 + bc2 (Wc1 frags from global/L2) --
    floatx4 acc2[4];
#pragma unroll
    for (int nt = 0; nt < 4; ++nt) acc2[nt] = (floatx4)0.0f;
    for (int c = 0; c < 4; ++c) {
        int kc = c * 32;
        short8_t a = *(const short8_t*)&Xs[(wave * 16 + m) * 136 + kc + kq * 8];
#pragma unroll
        for (int nt = 0; nt < 4; ++nt) {
            short8_t b = *(const short8_t*)(Wc1_t + (size_t)(nt * 16 + m) * 128 + kc + kq * 8);
            acc2[nt] = __builtin_amdgcn_mfma_f32_16x16x32_bf16(a, b, acc2[nt], 0, 0, 0);
        }
    }

    float w0v[4], w1v[4], bv[4];
#pragma unroll
    for (int nt = 0; nt < 4; ++nt) {
        int col = nt * 16 + m;
        w0v[nt] = Wc2[col * 2 + 0];
        w1v[nt] = Wc2[col * 2 + 1];
        bv[nt]  = bc1[col];
    }
    float b20 = bc2[0], b21 = bc2[1];
#pragma unroll
    for (int r = 0; r < 4; ++r) {
        float o0 = 0.f, o1 = 0.f;
#pragma unroll
        for (int nt = 0; nt < 4; ++nt) {
            float v = acc2[nt][r] + bv[nt];
            v = fmaxf(v, 0.f);
            o0 += v * w0v[nt];
            o1 += v * w1v[nt];
        }
#pragma unroll
        for (int off = 1; off < 16; off <<= 1) {
            o0 += __shfl_xor(o0, off, 64);
            o1 += __shfl_xor(o1, off, 64);
        }
        if (m == 0) {
            int row = rbw + kq * 4 + r;
            if (row < M) {
                out[(size_t)row * 2 + 0] = o0 + b20;
                out[(size_t)row * 2 + 1] = o1 + b21;
            }
        }
    }
}

extern "C" void kernel_launch(void* const* d_in, const int* in_sizes, int n_in,
                              void* d_out, int out_size, void* d_ws, size_t ws_size,
                              hipStream_t stream)
{
    const float* x_user  = (const float*)d_in[0];
    const float* x_pc    = (const float*)d_in[1];
    const float* x_url   = (const float*)d_in[2];
    const int* e_up_src  = (const int*)d_in[3];
    const int* e_up_dst  = (const int*)d_in[4];
    const int* e_uu_src  = (const int*)d_in[5];
    const int* e_uu_dst  = (const int*)d_in[6];
    const float* Wu      = (const float*)d_in[7];
    const float* bu      = (const float*)d_in[8];
    const float* Wp      = (const float*)d_in[9];
    const float* bp      = (const float*)d_in[10];
    const float* Wr_feat = (const float*)d_in[11];
    const float* br_feat = (const float*)d_in[12];
    const float* Wl_pc   = (const float*)d_in[13];
    const float* bl_pc   = (const float*)d_in[14];
    const float* Wr_pc   = (const float*)d_in[15];
    const float* Wl_url  = (const float*)d_in[16];
    const float* bl_url  = (const float*)d_in[17];
    const float* Wr_url  = (const float*)d_in[18];
    const float* Wctx    = (const float*)d_in[19];
    const float* bctx    = (const float*)d_in[20];
    const float* Wc1     = (const float*)d_in[21];
    const float* bc1     = (const float*)d_in[22];
    const float* Wc2     = (const float*)d_in[23];
    const float* bc2     = (const float*)d_in[24];
    float* out = (float*)d_out;

    // ---- workspace layout (4-byte words) ----
    char* wsb = (char*)d_ws;
    u16* user_bf  = (u16*)(wsb);                            //  6,400,000 w
    u16* enr      = (u16*)(wsb + 4ull *  6400000);          //  6,400,000 w
    u16* mean_pc  = (u16*)(wsb + 4ull * 12800000);          //  1,280,000 w
    u16* mean_url = (u16*)(wsb + 4ull * 14080000);          //  3,200,000 w
    u16* pc_a     = (u16*)(wsb + 4ull * 17280000);          //  1,280,000 w
    u16* pc_b     = (u16*)(wsb + 4ull * 18560000);          //  1,280,000 w
    u16* url_a    = (u16*)(wsb + 4ull * 19840000);          //  3,200,000 w
    u16* url_b    = (u16*)(wsb + 4ull * 23040000);          //  3,200,000 w
    u16* Wt       = (u16*)(wsb + 4ull * 26240000);          //    100,000 w slot
    int* cnts     = (int*)(wsb + 4ull * 26340000);          //    270,000 w (4 count arrays)
    int* up_dst_val = (int*)(wsb + 4ull * 26610000);        //    960,000 w (20000*48)
    int* uu_dst_val = (int*)(wsb + 4ull * 27570000);        //  2,000,000 w (50000*40)
    u16* up_src_val = (u16*)(wsb + 4ull * 29570000);        //  1,200,000 w (100000*24 u16)
    u16* uu_src_val = (u16*)(wsb + 4ull * 30770000);        //  1,200,000 w

    int* cnt_up_dst = cnts + 0;
    int* cnt_uu_dst = cnts + 20000;
    int* cnt_up_src = cnts + 70000;
    int* cnt_uu_src = cnts + 170000;

    const int T = 256;

    // 0. zero CSR counters
    hipMemsetAsync(cnts, 0, 270000ull * 4, stream);

    // 1. merged prep+fill: fill (1960, first) | wcvt (768) | proj3 (10625)
    PFArgs pf;
    pf.wsrc[0] = Wl_pc;               pf.wsrc[1] = Wr_pc;
    pf.wsrc[2] = Wl_pc + 128 * 128;   pf.wsrc[3] = Wr_pc + 128 * 128;
    pf.wsrc[4] = Wl_url;              pf.wsrc[5] = Wr_url;
    pf.wsrc[6] = Wl_url + 128 * 128;  pf.wsrc[7] = Wr_url + 128 * 128;
    pf.wsrc[8] = Wctx;                pf.wsrc[9] = Wctx + 128 * 128;
    pf.wsrc[10] = Wctx + 256 * 128;   pf.wsrc[11] = Wc1;
    pf.wdst = Wt;
    pf.Xu = x_user; pf.Wu = Wu;      pf.bu = bu;      pf.ou = user_bf;
    pf.Xp = x_pc;   pf.Wp = Wp;      pf.bp = bp;      pf.op = pc_a;
    pf.Xr = x_url;  pf.Wr = Wr_feat; pf.br = br_feat; pf.orr = url_a;
    pf.up_src = e_up_src; pf.up_dst = e_up_dst;
    pf.uu_src = e_uu_src; pf.uu_dst = e_uu_dst;
    pf.cnt_up_dst = cnt_up_dst; pf.cnt_uu_dst = cnt_uu_dst;
    pf.cnt_up_src = cnt_up_src; pf.cnt_uu_src = cnt_uu_src;
    pf.val_up_dst = up_dst_val; pf.val_uu_dst = uu_dst_val;
    pf.val_up_src = up_src_val; pf.val_uu_src = uu_src_val;
    prepfill_kernel<<<1960 + 768 + 10625, T, 0, stream>>>(pf);

    // 2. mean aggregation of user into pc/url (lean standalone kernel)
    gather_mean2_kernel<<<5000 + 12500, T, 0, stream>>>(
        user_bf, cnt_up_dst, up_dst_val, mean_pc, cnt_uu_dst, uu_dst_val, mean_url);

    // 3. fused GEMMs: pc chain | url chain | user@Wctx  (one dispatch)
    FArgs fg;
    fg.s[0] = { mean_pc,  pc_a,  Wt + 0 * 16384, Wt + 1 * 16384, Wt + 2 * 16384, Wt + 3 * 16384,
                Wt + 9 * 16384,  bl_pc,  bl_pc + 128,  pc_b,  N_PC_C,   0,   0 };
    fg.s[1] = { mean_url, url_a, Wt + 4 * 16384, Wt + 5 * 16384, Wt + 6 * 16384, Wt + 7 * 16384,
                Wt + 10 * 16384, bl_url, bl_url + 128, url_b, N_URL_C,  157, 0 };
    fg.s[2] = { user_bf,  nullptr, Wt + 8 * 16384, nullptr, nullptr, nullptr,
                nullptr,         bctx,   nullptr,      enr,   N_USER_C, 548, 1 };
    gemm_fused_kernel<<<548 + 782, T, 0, stream>>>(fg);

    // 4. fused ctx-gather + classifier (lean)
    ctx_final_kernel<<<(N_USER_C + 63) / 64, T, 0, stream>>>(
        enr, cnt_up_src, up_src_val, pc_b, cnt_uu_src, uu_src_val, url_b,
        Wt + 11 * 16384, bc1, Wc2, bc2, out, N_USER_C);
}